// Round 1
// baseline (50.855 us; speedup 1.0000x reference)
//
#include <hip/hip_runtime.h>
#include <math.h>

// LayerStatistics: out = (x copy [N floats], stats[5] = mean, sqmean, var(ddof=1), min, max)
// x: (32,64,128,128) fp32, N = 33554432. Memory-bound fused copy+reduce.

constexpr int BLOCK = 256;
constexpr int GRID  = 2048;   // 256 CU * 8 blocks/CU

// Pass 1: fused copy + per-block partial reduction.
// partials[b] = {sum, sumsq, min, max} for block b.
__global__ __launch_bounds__(BLOCK) void stats_pass1(const float4* __restrict__ in,
                                                     float4* __restrict__ out,
                                                     float4* __restrict__ partials,
                                                     int n4) {
    int tid    = blockIdx.x * blockDim.x + threadIdx.x;
    int stride = gridDim.x * blockDim.x;

    float s  = 0.0f;
    float ss = 0.0f;
    float mn =  INFINITY;
    float mx = -INFINITY;

    for (int i = tid; i < n4; i += stride) {
        float4 v = in[i];
        out[i] = v;
        s  += (v.x + v.y) + (v.z + v.w);
        ss += (v.x * v.x + v.y * v.y) + (v.z * v.z + v.w * v.w);
        mn = fminf(mn, fminf(fminf(v.x, v.y), fminf(v.z, v.w)));
        mx = fmaxf(mx, fmaxf(fmaxf(v.x, v.y), fmaxf(v.z, v.w)));
    }

    // wave (64-lane) butterfly-ish reduce via shfl_down
    #pragma unroll
    for (int off = 32; off > 0; off >>= 1) {
        s  += __shfl_down(s,  off, 64);
        ss += __shfl_down(ss, off, 64);
        mn = fminf(mn, __shfl_down(mn, off, 64));
        mx = fmaxf(mx, __shfl_down(mx, off, 64));
    }

    __shared__ float4 red[BLOCK / 64];
    int lane = threadIdx.x & 63;
    int wave = threadIdx.x >> 6;
    if (lane == 0) red[wave] = make_float4(s, ss, mn, mx);
    __syncthreads();

    if (threadIdx.x == 0) {
        float4 a = red[0];
        #pragma unroll
        for (int w = 1; w < BLOCK / 64; ++w) {
            float4 b = red[w];
            a.x += b.x;
            a.y += b.y;
            a.z = fminf(a.z, b.z);
            a.w = fmaxf(a.w, b.w);
        }
        partials[blockIdx.x] = a;
    }
}

// Pass 2: single block reduces GRID partials; double accumulation for sum/sumsq.
__global__ __launch_bounds__(BLOCK) void stats_pass2(const float4* __restrict__ partials,
                                                     float* __restrict__ stats_out,
                                                     int nparts, double n_total) {
    double s  = 0.0;
    double ss = 0.0;
    float  mn =  INFINITY;
    float  mx = -INFINITY;

    for (int i = threadIdx.x; i < nparts; i += blockDim.x) {
        float4 p = partials[i];
        s  += (double)p.x;
        ss += (double)p.y;
        mn = fminf(mn, p.z);
        mx = fmaxf(mx, p.w);
    }

    #pragma unroll
    for (int off = 32; off > 0; off >>= 1) {
        s  += __shfl_down(s,  off, 64);
        ss += __shfl_down(ss, off, 64);
        mn = fminf(mn, __shfl_down(mn, off, 64));
        mx = fmaxf(mx, __shfl_down(mx, off, 64));
    }

    __shared__ double sred[BLOCK / 64];
    __shared__ double ssred[BLOCK / 64];
    __shared__ float  mnred[BLOCK / 64];
    __shared__ float  mxred[BLOCK / 64];
    int lane = threadIdx.x & 63;
    int wave = threadIdx.x >> 6;
    if (lane == 0) { sred[wave] = s; ssred[wave] = ss; mnred[wave] = mn; mxred[wave] = mx; }
    __syncthreads();

    if (threadIdx.x == 0) {
        #pragma unroll
        for (int w = 1; w < BLOCK / 64; ++w) {
            s  += sred[w];
            ss += ssred[w];
            mn = fminf(mn, mnred[w]);
            mx = fmaxf(mx, mxred[w]);
        }
        double mean   = s / n_total;
        double sqmean = ss / n_total;
        double var    = (ss - s * s / n_total) / (n_total - 1.0);
        stats_out[0] = (float)mean;
        stats_out[1] = (float)sqmean;
        stats_out[2] = (float)var;
        stats_out[3] = mn;
        stats_out[4] = mx;
    }
}

extern "C" void kernel_launch(void* const* d_in, const int* in_sizes, int n_in,
                              void* d_out, int out_size, void* d_ws, size_t ws_size,
                              hipStream_t stream) {
    const float* x  = (const float*)d_in[0];
    float* out      = (float*)d_out;
    int n  = in_sizes[0];          // 33554432
    int n4 = n / 4;                // 8388608 (n divisible by 4)

    float4* partials = (float4*)d_ws;   // GRID * 16 B = 32 KiB

    stats_pass1<<<GRID, BLOCK, 0, stream>>>((const float4*)x, (float4*)out, partials, n4);
    stats_pass2<<<1, BLOCK, 0, stream>>>(partials, out + n, GRID, (double)n);
}